// Round 2
// baseline (482.028 us; speedup 1.0000x reference)
//
#include <hip/hip_runtime.h>

#define DEVINL __device__ __forceinline__

typedef __attribute__((ext_vector_type(8))) __bf16 bf16x8;
typedef __attribute__((ext_vector_type(4))) __bf16 bf16x4;
typedef __attribute__((ext_vector_type(4))) float f32x4;

// D = A(16x32) * B(32x16) + C, bf16 inputs, fp32 accum.
// A: m=lane&15, k=(lane>>4)*8+j ; B: n=lane&15, k=(lane>>4)*8+j
// C/D: col=lane&15, row=(lane>>4)*4+reg   [m89/m120-verified]
DEVINL f32x4 mfma16(bf16x8 a, bf16x8 b, f32x4 c) {
  return __builtin_amdgcn_mfma_f32_16x16x32_bf16(a, b, c, 0, 0, 0);
}

// Fragment of W^T: value[j] = W[kb+j][n]  (W stored (in,out), row-major 128x128)
DEVINL bf16x8 loadWfrag(const float* __restrict__ W, int kb, int n) {
  bf16x8 f;
#pragma unroll
  for (int j = 0; j < 8; ++j) f[j] = (__bf16)W[(kb + j) * 128 + n];
  return f;
}

// ---------------------------------------------------------------------------
// Kernel A: per (seq, 128-token chunk): K,V,Q projections (bf16 MFMA),
// elu+1 on K,Q; Q -> global ws (bf16, token-major); K^T,V^T -> LDS
// (wave-private rows); per-head KtV 32x32 + ksum accumulated, atomicAdd.
// grid = 128 seq x 16 chunks = 2048 blocks; 3 blocks/CU (LDS 54272*3 fits).
// Register double-buffer on the X staging tile.
// ---------------------------------------------------------------------------
__global__ __launch_bounds__(256, 3)
void qkv_ktv_kernel(const float* __restrict__ X,
                    const float* __restrict__ Wq, const float* __restrict__ bq,
                    const float* __restrict__ Wk, const float* __restrict__ bk,
                    const float* __restrict__ Wv, const float* __restrict__ bv,
                    __bf16* __restrict__ Qout,
                    float* __restrict__ ktvWs, float* __restrict__ ksumWs)
{
  __shared__ __bf16 Xs[64 * 136];   // [tok][e], pad 8 -> 2-way alias only
  __shared__ __bf16 Kt[128 * 72];   // [e][tok] transposed, pad 8
  __shared__ __bf16 Vt[128 * 72];

  const int tid  = threadIdx.x;
  const int lane = tid & 63;
  const int w    = tid >> 6;       // wave 0..3 (= head for KtV)
  const int l15  = lane & 15;
  const int quad = lane >> 4;
  const int s     = blockIdx.x >> 4;   // sequence 0..127
  const int chunk = blockIdx.x & 15;   // 128-token chunk
  const int tokc0 = chunk * 128;
  const float* Xseq = X + (size_t)s * 2048 * 128;

  // Register-resident weight fragments. Wave w owns out-dims [32w, 32w+32).
  bf16x8 wkF[2][4], wvF[2][4], wqF[2][4];
#pragma unroll
  for (int nt = 0; nt < 2; ++nt) {
    const int n = w * 32 + nt * 16 + l15;
#pragma unroll
    for (int kk = 0; kk < 4; ++kk) {
      const int kb = kk * 32 + quad * 8;
      wkF[nt][kk] = loadWfrag(Wk, kb, n);
      wvF[nt][kk] = loadWfrag(Wv, kb, n);
      wqF[nt][kk] = loadWfrag(Wq, kb, n);  // A-operand (orientation 2)
    }
  }
  float bkr[2], bvr[2], bqr[2][4];
#pragma unroll
  for (int nt = 0; nt < 2; ++nt) {
    bkr[nt] = bk[w * 32 + nt * 16 + l15];
    bvr[nt] = bv[w * 32 + nt * 16 + l15];
#pragma unroll
    for (int r = 0; r < 4; ++r)
      bqr[nt][r] = bq[w * 32 + nt * 16 + quad * 4 + r];
  }

  f32x4 accT[2][2] = {};          // per-head KtV accumulators [dt][et]
  float ksumAcc[2] = {0.f, 0.f};

  float4 pf[8];                   // register staging double-buffer
  {
    const float* Xtile = Xseq + (size_t)(tokc0) * 128;
#pragma unroll
    for (int i = 0; i < 8; ++i) {
      const int flat = tid + i * 256;
      pf[i] = *(const float4*)(Xtile + (flat >> 5) * 128 + (flat & 31) * 4);
    }
  }

  for (int t = 0; t < 2; ++t) {
    __syncthreads();  // Xs from prev iter fully consumed
#pragma unroll
    for (int i = 0; i < 8; ++i) {
      const int flat = tid + i * 256;
      bf16x4 b4;
      b4[0] = (__bf16)pf[i].x; b4[1] = (__bf16)pf[i].y;
      b4[2] = (__bf16)pf[i].z; b4[3] = (__bf16)pf[i].w;
      *(bf16x4*)(&Xs[(flat >> 5) * 136 + (flat & 31) * 4]) = b4;
    }
    __syncthreads();
    if (t == 0) {  // prefetch next tile; latency hides behind this iter's MFMAs
      const float* Xtile = Xseq + (size_t)(tokc0 + 64) * 128;
#pragma unroll
      for (int i = 0; i < 8; ++i) {
        const int flat = tid + i * 256;
        pf[i] = *(const float4*)(Xtile + (flat >> 5) * 128 + (flat & 31) * 4);
      }
    }

    // --- K & V projections, orientation 1: D[tok][e] = X @ W ---
#pragma unroll
    for (int mt = 0; mt < 4; ++mt) {
      f32x4 aK[2] = {}, aV[2] = {};
#pragma unroll
      for (int kk = 0; kk < 4; ++kk) {
        const bf16x8 ax = *(const bf16x8*)(&Xs[(mt * 16 + l15) * 136 + kk * 32 + quad * 8]);
        aK[0] = mfma16(ax, wkF[0][kk], aK[0]);
        aK[1] = mfma16(ax, wkF[1][kk], aK[1]);
        aV[0] = mfma16(ax, wvF[0][kk], aV[0]);
        aV[1] = mfma16(ax, wvF[1][kk], aV[1]);
      }
      // epilogue: bias (+ elu+1 for K); write transposed (lane holds 4
      // consecutive tokens at fixed e -> contiguous b64 store).
#pragma unroll
      for (int nt = 0; nt < 2; ++nt) {
        const int e    = w * 32 + nt * 16 + l15;
        const int tokb = mt * 16 + quad * 4;
        bf16x4 kq, vq;
        float ks = 0.f;
#pragma unroll
        for (int r = 0; r < 4; ++r) {
          float kv = aK[nt][r] + bkr[nt];
          kv = (kv > 0.f) ? (kv + 1.f) : __expf(kv);   // elu(x)+1
          ks += kv;
          kq[r] = (__bf16)kv;
          vq[r] = (__bf16)(aV[nt][r] + bvr[nt]);
        }
        ksumAcc[nt] += ks;
        *(bf16x4*)(&Kt[e * 72 + tokb]) = kq;
        *(bf16x4*)(&Vt[e * 72 + tokb]) = vq;
      }
    }

    // --- Q projection, orientation 2: D[e][tok] = W^T @ X^T ---
#pragma unroll
    for (int ntq = 0; ntq < 4; ++ntq) {
      f32x4 aQ[2] = {};
#pragma unroll
      for (int kk = 0; kk < 4; ++kk) {
        const bf16x8 bx = *(const bf16x8*)(&Xs[(ntq * 16 + l15) * 136 + kk * 32 + quad * 8]);
        aQ[0] = mfma16(wqF[0][kk], bx, aQ[0]);
        aQ[1] = mfma16(wqF[1][kk], bx, aQ[1]);
      }
      const int tok = tokc0 + t * 64 + ntq * 16 + l15;
      __bf16* qrow = Qout + ((size_t)s * 2048 + tok) * 128;
#pragma unroll
      for (int mt = 0; mt < 2; ++mt) {
        bf16x4 qq;
#pragma unroll
        for (int r = 0; r < 4; ++r) {
          float qv = aQ[mt][r] + bqr[mt][r];
          qv = (qv > 0.f) ? (qv + 1.f) : __expf(qv);
          qq[r] = (__bf16)qv;
        }
        *(bf16x4*)(qrow + w * 32 + mt * 16 + quad * 4) = qq;
      }
    }

    // --- KtV: wave w = head w. Reads ONLY rows this wave wrote (e in
    // [32w,32w+32)) -> intra-wave RAW, compiler lgkmcnt handles, no barrier.
#pragma unroll
    for (int kk = 0; kk < 2; ++kk) {
      bf16x8 aF[2], bF[2];
#pragma unroll
      for (int dt = 0; dt < 2; ++dt)
        aF[dt] = *(const bf16x8*)(&Kt[(w * 32 + dt * 16 + l15) * 72 + kk * 32 + quad * 8]);
#pragma unroll
      for (int et = 0; et < 2; ++et)
        bF[et] = *(const bf16x8*)(&Vt[(w * 32 + et * 16 + l15) * 72 + kk * 32 + quad * 8]);
#pragma unroll
      for (int dt = 0; dt < 2; ++dt)
#pragma unroll
        for (int et = 0; et < 2; ++et)
          accT[dt][et] = mfma16(aF[dt], bF[et], accT[dt][et]);
    }
  }

  // --- flush partials: ktv[s][h][d][e], ksum[s][e] (fp32 atomics) ---
  float* ktvH = ktvWs + ((size_t)s * 4 + w) * 1024;
#pragma unroll
  for (int dt = 0; dt < 2; ++dt)
#pragma unroll
    for (int et = 0; et < 2; ++et)
#pragma unroll
      for (int r = 0; r < 4; ++r)
        atomicAdd(&ktvH[(dt * 16 + quad * 4 + r) * 32 + et * 16 + l15], accT[dt][et][r]);

#pragma unroll
  for (int nt = 0; nt < 2; ++nt) {
    float v2 = ksumAcc[nt];
    v2 += __shfl_down(v2, 32);
    v2 += __shfl_down(v2, 16);
    if (quad == 0)
      atomicAdd(&ksumWs[s * 128 + w * 32 + nt * 16 + l15], v2);
  }
}

// ---------------------------------------------------------------------------
// Kernel B: per (seq, 128-token chunk): denom = q.ksum via one extra MFMA
// (replicated-ksum A-fragment -> every acc reg holds the denom for the
// lane's token); A2 = (q @ KtV_h) * Z; out = A2 @ Wo + bo.
// grid = 2048 blocks; LDS 34.8 KB -> 4 blocks/CU.
// ---------------------------------------------------------------------------
__global__ __launch_bounds__(256, 4)
void attn_out_kernel(const __bf16* __restrict__ Qin,
                     const float* __restrict__ ktvWs, const float* __restrict__ ksumWs,
                     const float* __restrict__ Wo, const float* __restrict__ bo,
                     float* __restrict__ Out)
{
  __shared__ __bf16 Qs[64 * 136];
  __shared__ __bf16 A2s[64 * 136];

  const int tid  = threadIdx.x;
  const int lane = tid & 63;
  const int w    = tid >> 6;   // wave = head
  const int l15  = lane & 15;
  const int quad = lane >> 4;
  const int s     = blockIdx.x >> 4;
  const int chunk = blockIdx.x & 15;

  // KtV_h as orientation-2 A-fragments: A[e'][d] = KtV[h][d][e']
  const float* ktvH = ktvWs + ((size_t)s * 4 + w) * 1024;
  bf16x8 aKtv[2];
#pragma unroll
  for (int mt = 0; mt < 2; ++mt)
#pragma unroll
    for (int j = 0; j < 8; ++j)
      aKtv[mt][j] = (__bf16)ktvH[(quad * 8 + j) * 32 + mt * 16 + l15];

  // Replicated-ksum fragment: A[m][k] = ksum_h[k] for all m -> D[*][tok] =
  // q[tok].ksum_h in every acc register of lane col=tok.
  bf16x8 aKs;
#pragma unroll
  for (int j = 0; j < 8; ++j)
    aKs[j] = (__bf16)ksumWs[s * 128 + w * 32 + quad * 8 + j];

  bf16x8 woF[2][4];
  float bor[2];
#pragma unroll
  for (int nt = 0; nt < 2; ++nt) {
    const int n = w * 32 + nt * 16 + l15;
    bor[nt] = bo[n];
#pragma unroll
    for (int kk = 0; kk < 4; ++kk)
      woF[nt][kk] = loadWfrag(Wo, kk * 32 + quad * 8, n);
  }

  const __bf16* Qseq = Qin + (size_t)s * 2048 * 128;
  bf16x8 qpf[4];
  {
    const __bf16* Qtile = Qseq + (size_t)(chunk * 128) * 128;
#pragma unroll
    for (int i = 0; i < 4; ++i) {
      const int c = tid + i * 256;
      qpf[i] = *(const bf16x8*)(Qtile + (c >> 4) * 128 + (c & 15) * 8);
    }
  }

  for (int t = 0; t < 2; ++t) {
    const int tok0 = chunk * 128 + t * 64;
    __syncthreads();
#pragma unroll
    for (int i = 0; i < 4; ++i) {
      const int c = tid + i * 256;
      *(bf16x8*)(&Qs[(c >> 4) * 136 + (c & 15) * 8]) = qpf[i];
    }
    __syncthreads();
    if (t == 0) {
      const __bf16* Qtile = Qseq + (size_t)(chunk * 128 + 64) * 128;
#pragma unroll
      for (int i = 0; i < 4; ++i) {
        const int c = tid + i * 256;
        qpf[i] = *(const bf16x8*)(Qtile + (c >> 4) * 128 + (c & 15) * 8);
      }
    }

    // --- GEMM2 (orientation 2): D[e'][tok] = KtV_h-frag @ Q^T; + denom MFMA
#pragma unroll
    for (int ntq = 0; ntq < 4; ++ntq) {
      const bf16x8 bq8 = *(const bf16x8*)(&Qs[(ntq * 16 + l15) * 136 + w * 32 + quad * 8]);
      f32x4 zero = {};
      f32x4 accD = mfma16(aKs, bq8, zero);
      f32x4 acc0 = mfma16(aKtv[0], bq8, zero);
      f32x4 acc1 = mfma16(aKtv[1], bq8, zero);
      const float z = 1.f / (accD[0] + 1e-6f);
      const int tokRow = ntq * 16 + l15;
      bf16x4 a4;
#pragma unroll
      for (int r = 0; r < 4; ++r) a4[r] = (__bf16)(acc0[r] * z);
      *(bf16x4*)(&A2s[tokRow * 136 + w * 32 + quad * 4]) = a4;
#pragma unroll
      for (int r = 0; r < 4; ++r) a4[r] = (__bf16)(acc1[r] * z);
      *(bf16x4*)(&A2s[tokRow * 136 + w * 32 + 16 + quad * 4]) = a4;
    }
    __syncthreads();  // A2s is cross-wave input to GEMM3

    // --- GEMM3 (orientation 1): out[tok][n] = A2 @ Wo + bo ---
#pragma unroll
    for (int mt = 0; mt < 4; ++mt) {
      f32x4 acc[2] = {};
#pragma unroll
      for (int kk = 0; kk < 4; ++kk) {
        const bf16x8 aa = *(const bf16x8*)(&A2s[(mt * 16 + l15) * 136 + kk * 32 + quad * 8]);
        acc[0] = mfma16(aa, woF[0][kk], acc[0]);
        acc[1] = mfma16(aa, woF[1][kk], acc[1]);
      }
      const int tokb = tok0 + mt * 16 + quad * 4;
      float* orow = Out + ((size_t)s * 2048 + tokb) * 128;
#pragma unroll
      for (int nt = 0; nt < 2; ++nt) {
        const int n = w * 32 + nt * 16 + l15;
#pragma unroll
        for (int r = 0; r < 4; ++r)
          orow[(size_t)r * 128 + n] = acc[nt][r] + bor[nt];
      }
    }
  }
}

extern "C" void kernel_launch(void* const* d_in, const int* in_sizes, int n_in,
                              void* d_out, int out_size, void* d_ws, size_t ws_size,
                              hipStream_t stream) {
  const float* X  = (const float*)d_in[0];
  const float* Wq = (const float*)d_in[1];
  const float* bq = (const float*)d_in[2];
  const float* Wk = (const float*)d_in[3];
  const float* bk = (const float*)d_in[4];
  const float* Wv = (const float*)d_in[5];
  const float* bv = (const float*)d_in[6];
  const float* Wo = (const float*)d_in[7];
  const float* bo = (const float*)d_in[8];
  float* Out = (float*)d_out;

  // ws: Q bf16 [128][2048][128] | ktv fp32 [128][4][32][32] | ksum fp32 [128][128]
  const size_t Q_BYTES    = (size_t)128 * 2048 * 128 * 2;
  const size_t KTV_BYTES  = (size_t)128 * 4 * 32 * 32 * 4;
  const size_t KSUM_BYTES = (size_t)128 * 128 * 4;
  __bf16* Qws   = (__bf16*)d_ws;
  float* ktvWs  = (float*)((char*)d_ws + Q_BYTES);
  float* ksumWs = (float*)((char*)d_ws + Q_BYTES + KTV_BYTES);

  hipMemsetAsync((char*)d_ws + Q_BYTES, 0, KTV_BYTES + KSUM_BYTES, stream);

  qkv_ktv_kernel<<<dim3(2048), dim3(256), 0, stream>>>(
      X, Wq, bq, Wk, bk, Wv, bv, Qws, ktvWs, ksumWs);
  attn_out_kernel<<<dim3(2048), dim3(256), 0, stream>>>(
      Qws, ktvWs, ksumWs, Wo, bo, Out);
}

// Round 3
// 317.111 us; speedup vs baseline: 1.5201x; 1.5201x over previous
//
#include <hip/hip_runtime.h>

#define DEVINL __device__ __forceinline__

typedef __attribute__((ext_vector_type(8))) __bf16 bf16x8;
typedef __attribute__((ext_vector_type(4))) __bf16 bf16x4;
typedef __attribute__((ext_vector_type(4))) float f32x4;

// D = A(16x32) * B(32x16) + C, bf16 inputs, fp32 accum.
// A: m=lane&15, k=(lane>>4)*8+j ; B: n=lane&15, k=(lane>>4)*8+j
// C/D: col=lane&15, row=(lane>>4)*4+reg   [m89/m120-verified]
DEVINL f32x4 mfma16(bf16x8 a, bf16x8 b, f32x4 c) {
  return __builtin_amdgcn_mfma_f32_16x16x32_bf16(a, b, c, 0, 0, 0);
}

// Fragment of W^T: value[j] = W[kb+j][n]  (W stored (in,out), row-major 128x128)
DEVINL bf16x8 loadWfrag(const float* __restrict__ W, int kb, int n) {
  bf16x8 f;
#pragma unroll
  for (int j = 0; j < 8; ++j) f[j] = (__bf16)W[(kb + j) * 128 + n];
  return f;
}

// ---------------------------------------------------------------------------
// Kernel A: per (seq, 256-token chunk): K,V projections (bf16 MFMA), elu+1
// on K; K^T,V^T -> LDS (wave-private rows); per-head KtV 32x32 + ksum,
// atomicAdd to ws. grid = 128 seq x 8 chunks = 1024 blocks.
// launch_bounds(256,2): R2 showed tighter bounds cause catastrophic spill;
// actual occupancy is LDS-capped at 3 blocks/CU (54272*3 <= 163840).
// ---------------------------------------------------------------------------
__global__ __launch_bounds__(256, 2)
void kv_ktv_kernel(const float* __restrict__ X,
                   const float* __restrict__ Wk, const float* __restrict__ bk,
                   const float* __restrict__ Wv, const float* __restrict__ bv,
                   float* __restrict__ ktvWs, float* __restrict__ ksumWs)
{
  __shared__ __bf16 Xs[64 * 136];   // [tok][e], pad 8 -> 2-way alias only
  __shared__ __bf16 Kt[128 * 72];   // [e][tok] transposed, pad 8
  __shared__ __bf16 Vt[128 * 72];

  const int tid  = threadIdx.x;
  const int lane = tid & 63;
  const int w    = tid >> 6;       // wave 0..3 (= head for KtV)
  const int l15  = lane & 15;
  const int quad = lane >> 4;
  const int s     = blockIdx.x >> 3;   // sequence 0..127
  const int chunk = blockIdx.x & 7;    // 256-token chunk
  const int tokc0 = chunk * 256;
  const float* Xseq = X + (size_t)s * 2048 * 128;

  // Register-resident weight fragments (wave w owns out-dims [32w,32w+32)).
  bf16x8 wkF[2][4], wvF[2][4];
#pragma unroll
  for (int nt = 0; nt < 2; ++nt) {
    const int n = w * 32 + nt * 16 + l15;
#pragma unroll
    for (int kk = 0; kk < 4; ++kk) {
      wkF[nt][kk] = loadWfrag(Wk, kk * 32 + quad * 8, n);
      wvF[nt][kk] = loadWfrag(Wv, kk * 32 + quad * 8, n);
    }
  }
  float bkr[2], bvr[2];
#pragma unroll
  for (int nt = 0; nt < 2; ++nt) {
    bkr[nt] = bk[w * 32 + nt * 16 + l15];
    bvr[nt] = bv[w * 32 + nt * 16 + l15];
  }

  f32x4 accT[2][2] = {};          // per-head KtV accumulators [dt][et]
  float ksumAcc[2] = {0.f, 0.f};

  for (int t = 0; t < 4; ++t) {
    const float* Xtile = Xseq + (size_t)(tokc0 + t * 64) * 128;
    __syncthreads();  // prev iter's Xs reads done
#pragma unroll
    for (int i = 0; i < 8; ++i) {
      const int flat = tid + i * 256;
      const float4 v = *(const float4*)(Xtile + (flat >> 5) * 128 + (flat & 31) * 4);
      bf16x4 b4;
      b4[0] = (__bf16)v.x; b4[1] = (__bf16)v.y;
      b4[2] = (__bf16)v.z; b4[3] = (__bf16)v.w;
      *(bf16x4*)(&Xs[(flat >> 5) * 136 + (flat & 31) * 4]) = b4;
    }
    __syncthreads();

    // --- K & V projections, orientation 1: D[tok][e] = X @ W ---
#pragma unroll
    for (int mt = 0; mt < 4; ++mt) {
      f32x4 aK[2] = {}, aV[2] = {};
#pragma unroll
      for (int kk = 0; kk < 4; ++kk) {
        const bf16x8 ax = *(const bf16x8*)(&Xs[(mt * 16 + l15) * 136 + kk * 32 + quad * 8]);
        aK[0] = mfma16(ax, wkF[0][kk], aK[0]);
        aK[1] = mfma16(ax, wkF[1][kk], aK[1]);
        aV[0] = mfma16(ax, wvF[0][kk], aV[0]);
        aV[1] = mfma16(ax, wvF[1][kk], aV[1]);
      }
      // epilogue: bias (+ elu+1 on K); lane holds 4 consecutive tokens at
      // fixed e -> contiguous b64 store into transposed Kt/Vt (own rows).
#pragma unroll
      for (int nt = 0; nt < 2; ++nt) {
        const int e    = w * 32 + nt * 16 + l15;
        const int tokb = mt * 16 + quad * 4;
        bf16x4 kq, vq;
        float ks = 0.f;
#pragma unroll
        for (int r = 0; r < 4; ++r) {
          float kv = aK[nt][r] + bkr[nt];
          kv = (kv > 0.f) ? (kv + 1.f) : __expf(kv);   // elu(x)+1
          ks += kv;
          kq[r] = (__bf16)kv;
          vq[r] = (__bf16)(aV[nt][r] + bvr[nt]);
        }
        ksumAcc[nt] += ks;
        *(bf16x4*)(&Kt[e * 72 + tokb]) = kq;
        *(bf16x4*)(&Vt[e * 72 + tokb]) = vq;
      }
    }

    // --- KtV: wave w = head w; reads only rows it wrote (intra-wave RAW,
    // in-order DS pipe, no barrier — verified R2) ---
#pragma unroll
    for (int kk = 0; kk < 2; ++kk) {
      bf16x8 aF[2], bF[2];
#pragma unroll
      for (int dt = 0; dt < 2; ++dt)
        aF[dt] = *(const bf16x8*)(&Kt[(w * 32 + dt * 16 + l15) * 72 + kk * 32 + quad * 8]);
#pragma unroll
      for (int et = 0; et < 2; ++et)
        bF[et] = *(const bf16x8*)(&Vt[(w * 32 + et * 16 + l15) * 72 + kk * 32 + quad * 8]);
#pragma unroll
      for (int dt = 0; dt < 2; ++dt)
#pragma unroll
        for (int et = 0; et < 2; ++et)
          accT[dt][et] = mfma16(aF[dt], bF[et], accT[dt][et]);
    }
  }

  // --- flush partials: ktv[s][h][d][e], ksum[s][e] (fp32 atomics) ---
  float* ktvH = ktvWs + ((size_t)s * 4 + w) * 1024;
#pragma unroll
  for (int dt = 0; dt < 2; ++dt)
#pragma unroll
    for (int et = 0; et < 2; ++et)
#pragma unroll
      for (int r = 0; r < 4; ++r)
        atomicAdd(&ktvH[(dt * 16 + quad * 4 + r) * 32 + et * 16 + l15], accT[dt][et][r]);

#pragma unroll
  for (int nt = 0; nt < 2; ++nt) {
    float v2 = ksumAcc[nt];
    v2 += __shfl_down(v2, 32);
    v2 += __shfl_down(v2, 16);
    if (quad == 0)
      atomicAdd(&ksumWs[s * 128 + w * 32 + nt * 16 + l15], v2);
  }
}

// ---------------------------------------------------------------------------
// Kernel B: per (seq, 256-token chunk): stage X; Q projection (orientation 2)
// + elu+1 -> LDS Qs (wave-private head slice); denom via replicated-ksum MFMA
// (R2-verified); A2 = (q @ KtV_h) * Z -> LDS (aliased onto Xs buffer);
// out = A2 @ Wo + bo. grid = 1024 blocks; LDS 34816 B -> 4 blocks/CU.
// ---------------------------------------------------------------------------
__global__ __launch_bounds__(256, 2)
void q_attn_out_kernel(const float* __restrict__ X,
                       const float* __restrict__ Wq, const float* __restrict__ bq,
                       const float* __restrict__ ktvWs, const float* __restrict__ ksumWs,
                       const float* __restrict__ Wo, const float* __restrict__ bo,
                       float* __restrict__ Out)
{
  __shared__ __bf16 XA[64 * 136];   // X tile, then (barrier) A2 tile
  __shared__ __bf16 Qs[64 * 136];   // Q[tok][e], wave-private head slices

  const int tid  = threadIdx.x;
  const int lane = tid & 63;
  const int w    = tid >> 6;   // wave = head
  const int l15  = lane & 15;
  const int quad = lane >> 4;
  const int s     = blockIdx.x >> 3;
  const int chunk = blockIdx.x & 7;
  const float* Xseq = X + (size_t)s * 2048 * 128;

  // KtV_h as orientation-2 A-fragments: A[e'][d] = KtV[h][d][e']
  const float* ktvH = ktvWs + ((size_t)s * 4 + w) * 1024;
  bf16x8 aKtv[2];
#pragma unroll
  for (int mt = 0; mt < 2; ++mt)
#pragma unroll
    for (int j = 0; j < 8; ++j)
      aKtv[mt][j] = (__bf16)ktvH[(quad * 8 + j) * 32 + mt * 16 + l15];

  // Replicated-ksum fragment: every acc reg of lane col=tok holds q.ksum_h.
  bf16x8 aKs;
#pragma unroll
  for (int j = 0; j < 8; ++j)
    aKs[j] = (__bf16)ksumWs[s * 128 + w * 32 + quad * 8 + j];

  // Wq as orientation-2 A-operand; Wo as orientation-1 B-operand.
  bf16x8 wqF[2][4], woF[2][4];
  float bqr[2][4], bor[2];
#pragma unroll
  for (int nt = 0; nt < 2; ++nt) {
    const int n = w * 32 + nt * 16 + l15;
    bor[nt] = bo[n];
#pragma unroll
    for (int kk = 0; kk < 4; ++kk) {
      wqF[nt][kk] = loadWfrag(Wq, kk * 32 + quad * 8, n);
      woF[nt][kk] = loadWfrag(Wo, kk * 32 + quad * 8, n);
    }
#pragma unroll
    for (int r = 0; r < 4; ++r)
      bqr[nt][r] = bq[w * 32 + nt * 16 + quad * 4 + r];
  }

  for (int t = 0; t < 4; ++t) {
    const int tok0 = chunk * 256 + t * 64;
    __syncthreads();  // prev GEMM3 done reading XA (as A2)
#pragma unroll
    for (int i = 0; i < 8; ++i) {
      const int flat = tid + i * 256;
      const float4 v = *(const float4*)(Xseq + (size_t)tok0 * 128 + (flat >> 5) * 128 + (flat & 31) * 4);
      bf16x4 b4;
      b4[0] = (__bf16)v.x; b4[1] = (__bf16)v.y;
      b4[2] = (__bf16)v.z; b4[3] = (__bf16)v.w;
      *(bf16x4*)(&XA[(flat >> 5) * 136 + (flat & 31) * 4]) = b4;
    }
    __syncthreads();

    // --- Q projection (orientation 2): D[e'][tok] = Wq^T @ X^T; elu+1;
    // lane holds 4 consecutive e' at fixed tok -> b64 store to Qs[tok][e'].
#pragma unroll
    for (int ntq = 0; ntq < 4; ++ntq) {
      f32x4 aQ[2] = {};
#pragma unroll
      for (int kk = 0; kk < 4; ++kk) {
        const bf16x8 bx = *(const bf16x8*)(&XA[(ntq * 16 + l15) * 136 + kk * 32 + quad * 8]);
        aQ[0] = mfma16(wqF[0][kk], bx, aQ[0]);
        aQ[1] = mfma16(wqF[1][kk], bx, aQ[1]);
      }
      const int tok = ntq * 16 + l15;
#pragma unroll
      for (int mt = 0; mt < 2; ++mt) {
        bf16x4 qq;
#pragma unroll
        for (int r = 0; r < 4; ++r) {
          float qv = aQ[mt][r] + bqr[mt][r];
          qv = (qv > 0.f) ? (qv + 1.f) : __expf(qv);
          qq[r] = (__bf16)qv;
        }
        *(bf16x4*)(&Qs[tok * 136 + w * 32 + mt * 16 + quad * 4]) = qq;
      }
    }
    __syncthreads();  // all waves done reading XA(X); reuse as A2

    // --- GEMM2: D[e'][tok] = KtV_h-frag @ Q^T + denom MFMA; *Z -> A2 ---
    // Qs reads are the wave's own head slice (intra-wave RAW, no barrier).
#pragma unroll
    for (int ntq = 0; ntq < 4; ++ntq) {
      const bf16x8 bq8 = *(const bf16x8*)(&Qs[(ntq * 16 + l15) * 136 + w * 32 + quad * 8]);
      f32x4 zero = {};
      f32x4 accD = mfma16(aKs, bq8, zero);
      f32x4 acc0 = mfma16(aKtv[0], bq8, zero);
      f32x4 acc1 = mfma16(aKtv[1], bq8, zero);
      const float z = 1.f / (accD[0] + 1e-6f);
      const int tokRow = ntq * 16 + l15;
      bf16x4 a4;
#pragma unroll
      for (int r = 0; r < 4; ++r) a4[r] = (__bf16)(acc0[r] * z);
      *(bf16x4*)(&XA[tokRow * 136 + w * 32 + quad * 4]) = a4;
#pragma unroll
      for (int r = 0; r < 4; ++r) a4[r] = (__bf16)(acc1[r] * z);
      *(bf16x4*)(&XA[tokRow * 136 + w * 32 + 16 + quad * 4]) = a4;
    }
    __syncthreads();  // A2 is cross-wave input to GEMM3

    // --- GEMM3 (orientation 1): out[tok][n] = A2 @ Wo + bo ---
#pragma unroll
    for (int mt = 0; mt < 4; ++mt) {
      f32x4 acc[2] = {};
#pragma unroll
      for (int kk = 0; kk < 4; ++kk) {
        const bf16x8 aa = *(const bf16x8*)(&XA[(mt * 16 + l15) * 136 + kk * 32 + quad * 8]);
        acc[0] = mfma16(aa, woF[0][kk], acc[0]);
        acc[1] = mfma16(aa, woF[1][kk], acc[1]);
      }
      const int tokb = tok0 + mt * 16 + quad * 4;
      float* orow = Out + ((size_t)s * 2048 + tokb) * 128;
#pragma unroll
      for (int nt = 0; nt < 2; ++nt) {
        const int n = w * 32 + nt * 16 + l15;
#pragma unroll
        for (int r = 0; r < 4; ++r)
          orow[(size_t)r * 128 + n] = acc[nt][r] + bor[nt];
      }
    }
  }
}

extern "C" void kernel_launch(void* const* d_in, const int* in_sizes, int n_in,
                              void* d_out, int out_size, void* d_ws, size_t ws_size,
                              hipStream_t stream) {
  const float* X  = (const float*)d_in[0];
  const float* Wq = (const float*)d_in[1];
  const float* bq = (const float*)d_in[2];
  const float* Wk = (const float*)d_in[3];
  const float* bk = (const float*)d_in[4];
  const float* Wv = (const float*)d_in[5];
  const float* bv = (const float*)d_in[6];
  const float* Wo = (const float*)d_in[7];
  const float* bo = (const float*)d_in[8];
  float* Out = (float*)d_out;

  // ws: ktv fp32 [128][4][32][32] | ksum fp32 [128][128]  (Q ws eliminated)
  const size_t KTV_BYTES  = (size_t)128 * 4 * 32 * 32 * 4;
  const size_t KSUM_BYTES = (size_t)128 * 128 * 4;
  float* ktvWs  = (float*)d_ws;
  float* ksumWs = (float*)((char*)d_ws + KTV_BYTES);

  hipMemsetAsync(d_ws, 0, KTV_BYTES + KSUM_BYTES, stream);

  kv_ktv_kernel<<<dim3(1024), dim3(256), 0, stream>>>(
      X, Wk, bk, Wv, bv, ktvWs, ksumWs);
  q_attn_out_kernel<<<dim3(1024), dim3(256), 0, stream>>>(
      X, Wq, bq, ktvWs, ksumWs, Wo, bo, Out);
}